// Round 15
// baseline (555.320 us; speedup 1.0000x reference)
//
#include <hip/hip_runtime.h>
#include <math.h>

// All tensors fp32. B=256, F=512, H=1024, C=1000.

typedef float nt4 __attribute__((ext_vector_type(4)));

__device__ __forceinline__ float4 ntload(const float4* p) {
    nt4 v = __builtin_nontemporal_load((const nt4*)p);
    return make_float4(v.x, v.y, v.z, v.w);
}

// ---------------------------------------------------------------------------
// pool_all: ONE dispatch for all pooling; NT loads (R13/R14-verified, at the
// ~3.4 TB/s read roofline). Do not touch.
// ---------------------------------------------------------------------------
struct PoolAll {
    const float* src[4];
    float*       dst[4];
    int n4[4];
    int cum[4];
    float inv[4];
    const float* s5;
    const float* ff;
    float*       dst5;
    float*       dstf;
    int nbb;
    int rows5;
};

__global__ __launch_bounds__(256) void pool_all_kernel(PoolAll S) {
    __shared__ float lds[64 * 49];
    if ((int)blockIdx.x < S.nbb) {
        int gid  = blockIdx.x * 256 + threadIdx.x;
        int wave = gid >> 6;
        int lane = gid & 63;
        if (wave >= S.cum[3]) return;
        int s = 0;
        #pragma unroll
        for (int i = 0; i < 3; ++i) if (wave >= S.cum[i]) s = i + 1;
        int row = wave - (s == 0 ? 0 : S.cum[s - 1]);
        const int n4 = S.n4[s];
        const float4* p4 = (const float4*)(S.src[s]) + (size_t)row * n4;
        float a0 = 0.f, a1 = 0.f, a2 = 0.f, a3 = 0.f;
        float a4 = 0.f, a5 = 0.f, a6 = 0.f, a7 = 0.f;
        int k = lane;
        for (; k + 448 < n4; k += 512) {
            float4 v0 = ntload(p4 + k);       float4 v1 = ntload(p4 + k + 64);
            float4 v2 = ntload(p4 + k + 128); float4 v3 = ntload(p4 + k + 192);
            float4 v4 = ntload(p4 + k + 256); float4 v5 = ntload(p4 + k + 320);
            float4 v6 = ntload(p4 + k + 384); float4 v7 = ntload(p4 + k + 448);
            a0 += (v0.x + v0.y) + (v0.z + v0.w);
            a1 += (v1.x + v1.y) + (v1.z + v1.w);
            a2 += (v2.x + v2.y) + (v2.z + v2.w);
            a3 += (v3.x + v3.y) + (v3.z + v3.w);
            a4 += (v4.x + v4.y) + (v4.z + v4.w);
            a5 += (v5.x + v5.y) + (v5.z + v5.w);
            a6 += (v6.x + v6.y) + (v6.z + v6.w);
            a7 += (v7.x + v7.y) + (v7.z + v7.w);
        }
        for (; k + 192 < n4; k += 256) {
            float4 v0 = ntload(p4 + k);       float4 v1 = ntload(p4 + k + 64);
            float4 v2 = ntload(p4 + k + 128); float4 v3 = ntload(p4 + k + 192);
            a0 += (v0.x + v0.y) + (v0.z + v0.w);
            a1 += (v1.x + v1.y) + (v1.z + v1.w);
            a2 += (v2.x + v2.y) + (v2.z + v2.w);
            a3 += (v3.x + v3.y) + (v3.z + v3.w);
        }
        for (; k < n4; k += 64) {
            float4 v = ntload(p4 + k);
            a0 += (v.x + v.y) + (v.z + v.w);
        }
        float acc = ((a0 + a1) + (a2 + a3)) + ((a4 + a5) + (a6 + a7));
        #pragma unroll
        for (int off = 32; off > 0; off >>= 1) acc += __shfl_down(acc, off, 64);
        if (lane == 0) S.dst[s][row] = acc * S.inv[s];
        return;
    }
    const int tid  = threadIdx.x;
    const int row0 = (blockIdx.x - S.nbb) * 64;
    const float* src;
    float* dst;
    int rbase;
    if (row0 < S.rows5) { src = S.s5; dst = S.dst5; rbase = row0; }
    else                { src = S.ff; dst = S.dstf; rbase = row0 - S.rows5; }
    const float4* p4 = (const float4*)(src + (size_t)rbase * 49);
    float4* l4 = (float4*)lds;
    float4 v0 = ntload(p4 + tid);
    float4 v1 = ntload(p4 + tid + 256);
    float4 v2 = ntload(p4 + tid + 512);
    float4 v3;
    const bool t3 = (tid < 784 - 768);
    if (t3) v3 = ntload(p4 + tid + 768);
    l4[tid]       = v0;
    l4[tid + 256] = v1;
    l4[tid + 512] = v2;
    if (t3) l4[tid + 768] = v3;
    __syncthreads();
    const int r  = tid >> 2;
    const int c0 = tid & 3;
    float s = 0.f;
    #pragma unroll
    for (int c = c0; c < 49; c += 4) s += lds[r * 49 + c];
    s += __shfl_down(s, 2, 64);
    s += __shfl_down(s, 1, 64);
    if (c0 == 0) dst[rbase + r] = s * (1.f / 49.f);
}

// ---------------------------------------------------------------------------
// fc_tile<XKS>: R6-verified LDS-tiled split-K SGEMM (tile 64x64, TK=16, 4x4
// micro, float4 staging, register prefetch).
//   XKS == 0:  X is a plain [M][K] activation.
//   XKS == 8/16: X is a partial slab [XKS][M][K]; the X-stage computes
//             relu(xbias[k] + sum_s X[s][m][k]) — prev layer's reduce_bias
//             fused into staging (ascending-s order = reduce_bias order).
// Writes partials Pt[ks][M][N]. Grids stay >= 512 blocks (no KS=1).
// ---------------------------------------------------------------------------
template <int XKS>
__device__ void fc_tile_body(const float* __restrict__ X,
        const float* __restrict__ xbias, const float* __restrict__ W,
        float* __restrict__ Pt, int M, int K, int N, int Kc, int ntiles,
        int bid, float (*Xs)[68], float (*Ws)[68]) {
    const int tpk = 4 * ntiles;            // mtiles=4
    int ks  = bid / tpk;
    int rem = bid - ks * tpk;
    int mt  = rem / ntiles;
    int nt  = rem - mt * ntiles;
    const int m0 = mt * 64, n0 = nt * 64;
    const int k0 = ks * Kc;
    int k1 = k0 + Kc; if (k1 > K) k1 = K;

    const int tid = threadIdx.x;
    const int tm = tid & 15;
    const int tn = tid >> 4;
    const int xr = tid >> 2, xc = tid & 3;
    const int wr = tid >> 4, wc = tid & 15;
    const int nwc = n0 + wc * 4;
    const size_t MK = (size_t)M * K;
    const size_t xrow = (size_t)(m0 + xr) * K;

    float4 acc[4];
    #pragma unroll
    for (int r = 0; r < 4; ++r) acc[r] = make_float4(0.f, 0.f, 0.f, 0.f);

    const int NXV = (XKS > 0) ? XKS : 1;
    float4 xv[NXV];
    float4 wv;

    {
        const size_t xo = xrow + k0 + xc * 4;
        #pragma unroll
        for (int ss = 0; ss < NXV; ++ss)
            xv[ss] = *(const float4*)(X + (size_t)ss * MK + xo);
        if (nwc + 3 < N) {
            wv = *(const float4*)(W + (size_t)(k0 + wr) * N + nwc);
        } else {
            wv.x = (nwc + 0 < N) ? W[(size_t)(k0 + wr) * N + nwc + 0] : 0.f;
            wv.y = (nwc + 1 < N) ? W[(size_t)(k0 + wr) * N + nwc + 1] : 0.f;
            wv.z = (nwc + 2 < N) ? W[(size_t)(k0 + wr) * N + nwc + 2] : 0.f;
            wv.w = (nwc + 3 < N) ? W[(size_t)(k0 + wr) * N + nwc + 3] : 0.f;
        }
    }

    for (int kt = k0; kt < k1; kt += 16) {
        __syncthreads();
        float4 xs = xv[0];
        if (XKS > 0) {
            #pragma unroll
            for (int ss = 1; ss < NXV; ++ss) {
                xs.x += xv[ss].x; xs.y += xv[ss].y;
                xs.z += xv[ss].z; xs.w += xv[ss].w;
            }
            float4 xb = *(const float4*)(xbias + kt + xc * 4);
            xs.x = fmaxf(xs.x + xb.x, 0.f);
            xs.y = fmaxf(xs.y + xb.y, 0.f);
            xs.z = fmaxf(xs.z + xb.z, 0.f);
            xs.w = fmaxf(xs.w + xb.w, 0.f);
        }
        Xs[xc * 4 + 0][xr] = xs.x;
        Xs[xc * 4 + 1][xr] = xs.y;
        Xs[xc * 4 + 2][xr] = xs.z;
        Xs[xc * 4 + 3][xr] = xs.w;
        *(float4*)&Ws[wr][wc * 4] = wv;
        __syncthreads();
        if (kt + 16 < k1) {
            const size_t xo = xrow + kt + 16 + xc * 4;
            #pragma unroll
            for (int ss = 0; ss < NXV; ++ss)
                xv[ss] = *(const float4*)(X + (size_t)ss * MK + xo);
            if (nwc + 3 < N) {
                wv = *(const float4*)(W + (size_t)(kt + 16 + wr) * N + nwc);
            } else {
                wv.x = (nwc + 0 < N) ? W[(size_t)(kt + 16 + wr) * N + nwc + 0] : 0.f;
                wv.y = (nwc + 1 < N) ? W[(size_t)(kt + 16 + wr) * N + nwc + 1] : 0.f;
                wv.z = (nwc + 2 < N) ? W[(size_t)(kt + 16 + wr) * N + nwc + 2] : 0.f;
                wv.w = (nwc + 3 < N) ? W[(size_t)(kt + 16 + wr) * N + nwc + 3] : 0.f;
            }
        }
        #pragma unroll
        for (int kk = 0; kk < 16; ++kk) {
            float4 xr4 = *(const float4*)&Xs[kk][tm * 4];
            float4 wr4 = *(const float4*)&Ws[kk][tn * 4];
            acc[0].x += xr4.x * wr4.x; acc[0].y += xr4.x * wr4.y;
            acc[0].z += xr4.x * wr4.z; acc[0].w += xr4.x * wr4.w;
            acc[1].x += xr4.y * wr4.x; acc[1].y += xr4.y * wr4.y;
            acc[1].z += xr4.y * wr4.z; acc[1].w += xr4.y * wr4.w;
            acc[2].x += xr4.z * wr4.x; acc[2].y += xr4.z * wr4.y;
            acc[2].z += xr4.z * wr4.z; acc[2].w += xr4.z * wr4.w;
            acc[3].x += xr4.w * wr4.x; acc[3].y += xr4.w * wr4.y;
            acc[3].z += xr4.w * wr4.z; acc[3].w += xr4.w * wr4.w;
        }
    }
    const int nbase = n0 + tn * 4;
    #pragma unroll
    for (int r = 0; r < 4; ++r) {
        int row = m0 + tm * 4 + r;
        float* pp = Pt + ((size_t)ks * M + row) * N + nbase;
        if (nbase + 3 < N) {
            *(float4*)pp = acc[r];
        } else {
            float vv[4] = { acc[r].x, acc[r].y, acc[r].z, acc[r].w };
            for (int c = 0; c < 4; ++c) if (nbase + c < N) pp[c] = vv[c];
        }
    }
}

template <int XKS>
__global__ __launch_bounds__(256) void fc_tile_kernel(const float* __restrict__ X,
        const float* __restrict__ xbias, const float* __restrict__ W,
        float* __restrict__ Pt, int M, int K, int N, int Kc, int ntiles) {
    __shared__ __align__(16) float Xs[16][68];
    __shared__ __align__(16) float Ws[16][68];
    fc_tile_body<XKS>(X, xbias, W, Pt, M, K, N, Kc, ntiles, blockIdx.x, Xs, Ws);
}

// Sum KS partial slices + bias (+ReLU). R6-verified. N % 4 == 0.
__global__ __launch_bounds__(256) void reduce_bias_kernel(const float* __restrict__ P,
        const float* __restrict__ bias, float* __restrict__ Y,
        int MN, int N, int KS, int do_relu) {
    int i = (blockIdx.x * 256 + threadIdx.x) * 4;
    if (i >= MN) return;
    float4 a = *(const float4*)(P + i);
    for (int s = 1; s < KS; ++s) {
        float4 b = *(const float4*)(P + (size_t)s * MN + i);
        a.x += b.x; a.y += b.y; a.z += b.z; a.w += b.w;
    }
    int n = i - (i / N) * N;
    float4 bb = *(const float4*)(bias + n);
    a.x += bb.x; a.y += bb.y; a.z += bb.z; a.w += bb.w;
    if (do_relu) {
        a.x = fmaxf(a.x, 0.f); a.y = fmaxf(a.y, 0.f);
        a.z = fmaxf(a.z, 0.f); a.w = fmaxf(a.w, 0.f);
    }
    *(float4*)(Y + i) = a;
}

// ---------------------------------------------------------------------------
// proj_body: projection GEMM task (TK=8, verified R6..R14). Bias fused.
// ---------------------------------------------------------------------------
struct ProjParams {
    const float* W[5];
    const float* bp[5];
    const float* g[5];
    const float* be[5];
    int K[5];
    int poff[5];
};

__device__ void proj_body(const ProjParams& P, const float* __restrict__ pools,
        float* __restrict__ proj_out, int task,
        float (*Xs)[68], float (*Ws)[68]) {
    const int st  = task >> 5;
    const int bid = task & 31;
    const int K  = P.K[st];
    const float* X = pools + P.poff[st];
    const float* W = P.W[st];
    const int N = 512;
    int mt  = bid >> 3;
    int nt  = bid & 7;
    const int m0 = mt * 64, n0 = nt * 64;

    const int tid = threadIdx.x;
    const int tm = tid & 15;
    const int tn = tid >> 4;
    const int xa = tid >> 3, xb = tid & 7;
    const int wc = tid & 63, wb = tid >> 6;
    const int nw = n0 + wc;

    float4 acc[4];
    #pragma unroll
    for (int r = 0; r < 4; ++r) acc[r] = make_float4(0.f, 0.f, 0.f, 0.f);

    float x0, x1, w0v, w1v;
    x0  = X[(size_t)(m0 + xa) * K + xb];
    x1  = X[(size_t)(m0 + xa + 32) * K + xb];
    w0v = W[(size_t)wb * N + nw];
    w1v = W[(size_t)(wb + 4) * N + nw];

    for (int kt = 0; kt < K; kt += 8) {
        __syncthreads();
        Xs[xb][xa] = x0; Xs[xb][xa + 32] = x1;
        Ws[wb][wc] = w0v; Ws[wb + 4][wc] = w1v;
        __syncthreads();
        if (kt + 8 < K) {
            x0  = X[(size_t)(m0 + xa) * K + kt + 8 + xb];
            x1  = X[(size_t)(m0 + xa + 32) * K + kt + 8 + xb];
            w0v = W[(size_t)(kt + 8 + wb) * N + nw];
            w1v = W[(size_t)(kt + 8 + wb + 4) * N + nw];
        }
        #pragma unroll
        for (int kk = 0; kk < 8; ++kk) {
            float4 xr = *(const float4*)&Xs[kk][tm * 4];
            float4 wr = *(const float4*)&Ws[kk][tn * 4];
            acc[0].x += xr.x * wr.x; acc[0].y += xr.x * wr.y;
            acc[0].z += xr.x * wr.z; acc[0].w += xr.x * wr.w;
            acc[1].x += xr.y * wr.x; acc[1].y += xr.y * wr.y;
            acc[1].z += xr.y * wr.z; acc[1].w += xr.y * wr.w;
            acc[2].x += xr.z * wr.x; acc[2].y += xr.z * wr.y;
            acc[2].z += xr.z * wr.z; acc[2].w += xr.z * wr.w;
            acc[3].x += xr.w * wr.x; acc[3].y += xr.w * wr.y;
            acc[3].z += xr.w * wr.z; acc[3].w += xr.w * wr.w;
        }
    }
    const int nbase = n0 + tn * 4;
    float4 bb = *(const float4*)(P.bp[st] + nbase);
    float* op = proj_out + (size_t)st * 131072 + (size_t)(m0 + tm * 4) * N + nbase;
    #pragma unroll
    for (int r = 0; r < 4; ++r) {
        float4 v = acc[r];
        v.x += bb.x; v.y += bb.y; v.z += bb.z; v.w += bb.w;
        *(float4*)(op + (size_t)r * N) = v;
    }
}

// gate1 split-K (512 blocks) + proj (160 tasks) merged: independent work.
__global__ __launch_bounds__(256) void gate1_proj_kernel(
        const float* __restrict__ gate_in, const float* __restrict__ Wg1,
        float* __restrict__ slab, ProjParams P,
        const float* __restrict__ pools, float* __restrict__ proj_out) {
    __shared__ __align__(16) float Xs[16][68];
    __shared__ __align__(16) float Ws[16][68];
    if (blockIdx.x < 512) {
        fc_tile_body<0>(gate_in, nullptr, Wg1, slab, 256, 960, 1024, 128, 16,
                        blockIdx.x, Xs, Ws);
    } else {
        proj_body(P, pools, proj_out, blockIdx.x - 512,
                  (float(*)[68])Xs, (float(*)[68])Ws);
    }
}

// ---------------------------------------------------------------------------
// fc3 + mixln fused; fc3 input = gate2's 16 partial slices, reduced inline
// (ascending s + bg2 + relu — identical order to reduce_bias).
// ---------------------------------------------------------------------------
__global__ __launch_bounds__(256) void fc3_mixln_kernel(
        const float* __restrict__ Xp, const float* __restrict__ bg2,
        const float* __restrict__ Wg3, const float* __restrict__ bg3,
        ProjParams P, const float* __restrict__ proj_out,
        float* __restrict__ mix, float* __restrict__ out_gl,
        float* __restrict__ out_topi, float* __restrict__ out_w) {
    const int b    = blockIdx.x;
    const int tid  = threadIdx.x;
    const int lane = tid & 63;
    const int wv   = tid >> 6;
    __shared__ float red[4][5];
    __shared__ int   s_i0, s_i1;
    __shared__ float s_w0, s_w1;
    __shared__ float redS[4], redQ[4];
    __shared__ float s_mu, s_rstd;

    // ---- phase 1: gate fc3 (inline 16-slice reduce) + top2 + softmax ----
    {
        const size_t MK = (size_t)256 * 512;
        float acc[5] = {0.f, 0.f, 0.f, 0.f, 0.f};
        for (int k = tid; k < 512; k += 256) {
            float v = Xp[(size_t)b * 512 + k];
            #pragma unroll
            for (int s = 1; s < 16; ++s)
                v += Xp[(size_t)s * MK + (size_t)b * 512 + k];
            float xv = fmaxf(v + bg2[k], 0.f);
            const float* wr = Wg3 + (size_t)k * 5;
            acc[0] += xv * wr[0]; acc[1] += xv * wr[1]; acc[2] += xv * wr[2];
            acc[3] += xv * wr[3]; acc[4] += xv * wr[4];
        }
        #pragma unroll
        for (int off = 32; off > 0; off >>= 1) {
            #pragma unroll
            for (int j = 0; j < 5; ++j) acc[j] += __shfl_down(acc[j], off, 64);
        }
        if (lane == 0) {
            #pragma unroll
            for (int j = 0; j < 5; ++j) red[wv][j] = acc[j];
        }
        __syncthreads();
        if (tid == 0) {
            float v[5];
            #pragma unroll
            for (int j = 0; j < 5; ++j)
                v[j] = ((red[0][j] + red[1][j]) + (red[2][j] + red[3][j])) + bg3[j];
            int i0 = 0;
            #pragma unroll
            for (int i = 1; i < 5; ++i) if (v[i] > v[i0]) i0 = i;
            int i1 = -1;
            #pragma unroll
            for (int i = 0; i < 5; ++i) {
                if (i == i0) continue;
                if (i1 < 0 || v[i] > v[i1]) i1 = i;
            }
            float e1 = __expf(v[i1] - v[i0]);
            float inv = 1.f / (1.f + e1);
            float w0 = inv, w1 = e1 * inv;
            s_i0 = i0; s_i1 = i1; s_w0 = w0; s_w1 = w1;
            #pragma unroll
            for (int j = 0; j < 5; ++j) out_gl[b * 5 + j] = v[j];
            out_topi[b * 2]     = (float)i0;
            out_topi[b * 2 + 1] = (float)i1;
            out_w[b * 2]     = w0;
            out_w[b * 2 + 1] = w1;
        }
    }
    __syncthreads();

    // ---- phase 2: mixln (f = tid and tid+256) ----
    float a0 = 0.f, a1 = 0.f;
    const int i0 = s_i0, i1 = s_i1;
    const float w0 = s_w0, w1 = s_w1;
    for (int j = 0; j < 2; ++j) {
        __syncthreads();
        const int st = j ? i1 : i0;
        const float w = j ? w1 : w0;
        const float* pp = proj_out + (size_t)st * 131072 + (size_t)b * 512;
        float h0 = pp[tid];
        float h1 = pp[tid + 256];
        float s = h0 + h1, q = h0 * h0 + h1 * h1;
        #pragma unroll
        for (int off = 32; off > 0; off >>= 1) {
            s += __shfl_down(s, off, 64);
            q += __shfl_down(q, off, 64);
        }
        if (lane == 0) { redS[wv] = s; redQ[wv] = q; }
        __syncthreads();
        if (tid == 0) {
            float ts = (redS[0] + redS[1]) + (redS[2] + redS[3]);
            float tq = (redQ[0] + redQ[1]) + (redQ[2] + redQ[3]);
            float mu  = ts * (1.f / 512.f);
            float var = tq * (1.f / 512.f) - mu * mu;
            s_mu   = mu;
            s_rstd = rsqrtf(var + 1e-5f);
        }
        __syncthreads();
        float mu = s_mu, rstd = s_rstd;
        float x0 = (h0 - mu) * rstd * P.g[st][tid] + P.be[st][tid];
        float x1 = (h1 - mu) * rstd * P.g[st][tid + 256] + P.be[st][tid + 256];
        a0 += w * (0.5f * x0 * (1.f + erff(x0 * 0.70710678118654752f)));
        a1 += w * (0.5f * x1 * (1.f + erff(x1 * 0.70710678118654752f)));
    }
    mix[(size_t)b * 512 + tid]       = a0;
    mix[(size_t)b * 512 + tid + 256] = a1;
}

// ---------------------------------------------------------------------------
extern "C" void kernel_launch(void* const* d_in, const int* in_sizes, int n_in,
                              void* d_out, int out_size, void* d_ws, size_t ws_size,
                              hipStream_t stream) {
    const int B = 256;

    const float* s1 = (const float*)d_in[0];
    const float* s2 = (const float*)d_in[1];
    const float* s3 = (const float*)d_in[2];
    const float* s4 = (const float*)d_in[3];
    const float* s5 = (const float*)d_in[4];
    const float* ff = (const float*)d_in[5];
    const float *Wp[5], *bp[5], *g[5], *be[5];
    for (int i = 0; i < 5; ++i) {
        Wp[i] = (const float*)d_in[6 + 4 * i];
        bp[i] = (const float*)d_in[7 + 4 * i];
        g[i]  = (const float*)d_in[8 + 4 * i];
        be[i] = (const float*)d_in[9 + 4 * i];
    }
    const float* Wg1 = (const float*)d_in[26]; const float* bg1 = (const float*)d_in[27];
    const float* Wg2 = (const float*)d_in[28]; const float* bg2 = (const float*)d_in[29];
    const float* Wg3 = (const float*)d_in[30]; const float* bg3 = (const float*)d_in[31];
    const float* Wc1 = (const float*)d_in[32]; const float* bc1 = (const float*)d_in[33];
    const float* Wc2 = (const float*)d_in[34]; const float* bc2 = (const float*)d_in[35];
    const float* Wc3 = (const float*)d_in[36]; const float* bc3 = (const float*)d_in[37];

    // ---- workspace layout (fp32 elements) ----
    float* ws = (float*)d_ws;
    const int Ks[5]   = {16, 24, 40, 80, 160};
    const int poff[5] = {0, 4096, 10240, 20480, 40960};
    float* pools    = ws;                                     // 81920
    float* gate_in  = ws + 81920;                             // 245760
    float* mix      = ws + 327680;                            // 131072
    float* proj_out = ws + 458752;                            // 655360
    float* slabA    = ws + 1114112;                           // 4194304 (16MB)
    float* slabB    = ws + 5308416;                           // 4194304 (16MB)

    float* out      = (float*)d_out;
    float* out_gl   = out + 256000;
    float* out_topi = out + 257280;
    float* out_w    = out + 257792;

    // ---- 1) ALL pooling in one dispatch (NT loads) ----
    {
        PoolAll S;
        const float* srcs[4] = { s1, s2, s3, s4 };
        const int rls[4]  = { 112 * 112, 56 * 56, 28 * 28, 14 * 14 };
        const int rows[4] = { B * 16, B * 24, B * 40, B * 80 };
        int cum = 0;
        for (int i = 0; i < 4; ++i) {
            S.src[i] = srcs[i]; S.dst[i] = pools + poff[i]; S.n4[i] = rls[i] / 4;
            cum += rows[i]; S.cum[i] = cum; S.inv[i] = 1.f / rls[i];
        }
        S.nbb   = (cum * 64) / 256;           // 10240
        S.s5    = s5; S.ff = ff;
        S.dst5  = pools + poff[4]; S.dstf = gate_in;
        S.rows5 = B * 160;
        int small_blocks = (S.rows5 + B * 960) / 64;   // 4480
        pool_all_kernel<<<S.nbb + small_blocks, 256, 0, stream>>>(S);
    }

    ProjParams P;
    for (int i = 0; i < 5; ++i) {
        P.W[i] = Wp[i]; P.bp[i] = bp[i]; P.g[i] = g[i]; P.be[i] = be[i];
        P.K[i] = Ks[i]; P.poff[i] = poff[i];
    }

    // ---- 2) gate1 split-K (KS=8, 512 blocks) + proj, one dispatch -> slabA
    gate1_proj_kernel<<<512 + 160, 256, 0, stream>>>(gate_in, Wg1, slabA,
                                                     P, pools, proj_out);
    // ---- 3) gate2: XKS=8 fused reduce(bg1,relu), KS=16 (512 blocks) -> slabB
    fc_tile_kernel<8><<<16 * 4 * 8, 256, 0, stream>>>(
        slabA, bg1, Wg2, slabB, 256, 1024, 512, 64, 8);
    // ---- 4) fc3 (inline 16-slice reduce + bg2 + relu) + top2 + mixln ----
    fc3_mixln_kernel<<<B, 256, 0, stream>>>(slabB, bg2, Wg3, bg3, P, proj_out,
                                            mix, out_gl, out_topi, out_w);
    // ---- 5) cls1: KS=16 Kc=32 (1024 blocks, 4/CU) -> slabA[16][256][1024]
    fc_tile_kernel<0><<<16 * 4 * 16, 256, 0, stream>>>(
        mix, nullptr, Wc1, slabA, 256, 512, 1024, 32, 16);
    // ---- 6) cls2: XKS=16 fused reduce(bc1,relu), KS=16 (512 blocks) -> slabB
    fc_tile_kernel<16><<<16 * 4 * 8, 256, 0, stream>>>(
        slabA, bc1, Wc2, slabB, 256, 1024, 512, 64, 8);
    // ---- 7) cls3: XKS=16 fused reduce(bc2,relu), KS=8 (512 blocks) -> slabA
    fc_tile_kernel<16><<<8 * 4 * 16, 256, 0, stream>>>(
        slabB, bc2, Wc3, slabA, 256, 512, 1000, 64, 16);
    // ---- 8) final reduce + bc3 -> out logits
    reduce_bias_kernel<<<(256 * 1000 / 4 + 255) / 256, 256, 0, stream>>>(
        slabA, bc3, out, 256 * 1000, 1000, 8, 0);
}

// Round 16
// 524.796 us; speedup vs baseline: 1.0582x; 1.0582x over previous
//
#include <hip/hip_runtime.h>
#include <math.h>

// All tensors fp32. B=256, F=512, H=1024, C=1000.
// R14 configuration — session best (525 us). XKS=8 staging-fused reductions,
// grids >= 256 blocks, 8 post-pool dispatch nodes.

typedef float nt4 __attribute__((ext_vector_type(4)));

__device__ __forceinline__ float4 ntload(const float4* p) {
    nt4 v = __builtin_nontemporal_load((const nt4*)p);
    return make_float4(v.x, v.y, v.z, v.w);
}

// ---------------------------------------------------------------------------
// pool_all: ONE dispatch for all pooling; NT loads (R13/R14-verified, at the
// ~3.4 TB/s read roofline). Do not touch.
// ---------------------------------------------------------------------------
struct PoolAll {
    const float* src[4];
    float*       dst[4];
    int n4[4];
    int cum[4];
    float inv[4];
    const float* s5;
    const float* ff;
    float*       dst5;
    float*       dstf;
    int nbb;
    int rows5;
};

__global__ __launch_bounds__(256) void pool_all_kernel(PoolAll S) {
    __shared__ float lds[64 * 49];
    if ((int)blockIdx.x < S.nbb) {
        int gid  = blockIdx.x * 256 + threadIdx.x;
        int wave = gid >> 6;
        int lane = gid & 63;
        if (wave >= S.cum[3]) return;
        int s = 0;
        #pragma unroll
        for (int i = 0; i < 3; ++i) if (wave >= S.cum[i]) s = i + 1;
        int row = wave - (s == 0 ? 0 : S.cum[s - 1]);
        const int n4 = S.n4[s];
        const float4* p4 = (const float4*)(S.src[s]) + (size_t)row * n4;
        float a0 = 0.f, a1 = 0.f, a2 = 0.f, a3 = 0.f;
        float a4 = 0.f, a5 = 0.f, a6 = 0.f, a7 = 0.f;
        int k = lane;
        for (; k + 448 < n4; k += 512) {
            float4 v0 = ntload(p4 + k);       float4 v1 = ntload(p4 + k + 64);
            float4 v2 = ntload(p4 + k + 128); float4 v3 = ntload(p4 + k + 192);
            float4 v4 = ntload(p4 + k + 256); float4 v5 = ntload(p4 + k + 320);
            float4 v6 = ntload(p4 + k + 384); float4 v7 = ntload(p4 + k + 448);
            a0 += (v0.x + v0.y) + (v0.z + v0.w);
            a1 += (v1.x + v1.y) + (v1.z + v1.w);
            a2 += (v2.x + v2.y) + (v2.z + v2.w);
            a3 += (v3.x + v3.y) + (v3.z + v3.w);
            a4 += (v4.x + v4.y) + (v4.z + v4.w);
            a5 += (v5.x + v5.y) + (v5.z + v5.w);
            a6 += (v6.x + v6.y) + (v6.z + v6.w);
            a7 += (v7.x + v7.y) + (v7.z + v7.w);
        }
        for (; k + 192 < n4; k += 256) {
            float4 v0 = ntload(p4 + k);       float4 v1 = ntload(p4 + k + 64);
            float4 v2 = ntload(p4 + k + 128); float4 v3 = ntload(p4 + k + 192);
            a0 += (v0.x + v0.y) + (v0.z + v0.w);
            a1 += (v1.x + v1.y) + (v1.z + v1.w);
            a2 += (v2.x + v2.y) + (v2.z + v2.w);
            a3 += (v3.x + v3.y) + (v3.z + v3.w);
        }
        for (; k < n4; k += 64) {
            float4 v = ntload(p4 + k);
            a0 += (v.x + v.y) + (v.z + v.w);
        }
        float acc = ((a0 + a1) + (a2 + a3)) + ((a4 + a5) + (a6 + a7));
        #pragma unroll
        for (int off = 32; off > 0; off >>= 1) acc += __shfl_down(acc, off, 64);
        if (lane == 0) S.dst[s][row] = acc * S.inv[s];
        return;
    }
    const int tid  = threadIdx.x;
    const int row0 = (blockIdx.x - S.nbb) * 64;
    const float* src;
    float* dst;
    int rbase;
    if (row0 < S.rows5) { src = S.s5; dst = S.dst5; rbase = row0; }
    else                { src = S.ff; dst = S.dstf; rbase = row0 - S.rows5; }
    const float4* p4 = (const float4*)(src + (size_t)rbase * 49);
    float4* l4 = (float4*)lds;
    float4 v0 = ntload(p4 + tid);
    float4 v1 = ntload(p4 + tid + 256);
    float4 v2 = ntload(p4 + tid + 512);
    float4 v3;
    const bool t3 = (tid < 784 - 768);
    if (t3) v3 = ntload(p4 + tid + 768);
    l4[tid]       = v0;
    l4[tid + 256] = v1;
    l4[tid + 512] = v2;
    if (t3) l4[tid + 768] = v3;
    __syncthreads();
    const int r  = tid >> 2;
    const int c0 = tid & 3;
    float s = 0.f;
    #pragma unroll
    for (int c = c0; c < 49; c += 4) s += lds[r * 49 + c];
    s += __shfl_down(s, 2, 64);
    s += __shfl_down(s, 1, 64);
    if (c0 == 0) dst[rbase + r] = s * (1.f / 49.f);
}

// ---------------------------------------------------------------------------
// fc_tile<XKS>: R6-verified LDS-tiled split-K SGEMM (tile 64x64, TK=16, 4x4
// micro, float4 staging, register prefetch).
//   XKS == 0: X is a plain [M][K] activation.
//   XKS == 8: X is a partial slab [8][M][K]; the X-stage computes
//             relu(xbias[k] + sum_s X[s][m][k]) — prev layer's reduce_bias
//             fused into staging (ascending-s order = reduce_bias order).
// Writes partials Pt[ks][M][N]. Grids stay 256-512 blocks (no KS=1).
// XKS=16 measured WORSE (R15: +30 us) — register pressure + slab traffic.
// ---------------------------------------------------------------------------
template <int XKS>
__device__ void fc_tile_body(const float* __restrict__ X,
        const float* __restrict__ xbias, const float* __restrict__ W,
        float* __restrict__ Pt, int M, int K, int N, int Kc, int ntiles,
        int bid, float (*Xs)[68], float (*Ws)[68]) {
    const int tpk = 4 * ntiles;            // mtiles=4
    int ks  = bid / tpk;
    int rem = bid - ks * tpk;
    int mt  = rem / ntiles;
    int nt  = rem - mt * ntiles;
    const int m0 = mt * 64, n0 = nt * 64;
    const int k0 = ks * Kc;
    int k1 = k0 + Kc; if (k1 > K) k1 = K;

    const int tid = threadIdx.x;
    const int tm = tid & 15;
    const int tn = tid >> 4;
    const int xr = tid >> 2, xc = tid & 3;
    const int wr = tid >> 4, wc = tid & 15;
    const int nwc = n0 + wc * 4;
    const size_t MK = (size_t)M * K;
    const size_t xrow = (size_t)(m0 + xr) * K;

    float4 acc[4];
    #pragma unroll
    for (int r = 0; r < 4; ++r) acc[r] = make_float4(0.f, 0.f, 0.f, 0.f);

    const int NXV = (XKS > 0) ? XKS : 1;
    float4 xv[NXV];
    float4 wv;

    {
        const size_t xo = xrow + k0 + xc * 4;
        #pragma unroll
        for (int ss = 0; ss < NXV; ++ss)
            xv[ss] = *(const float4*)(X + (size_t)ss * MK + xo);
        if (nwc + 3 < N) {
            wv = *(const float4*)(W + (size_t)(k0 + wr) * N + nwc);
        } else {
            wv.x = (nwc + 0 < N) ? W[(size_t)(k0 + wr) * N + nwc + 0] : 0.f;
            wv.y = (nwc + 1 < N) ? W[(size_t)(k0 + wr) * N + nwc + 1] : 0.f;
            wv.z = (nwc + 2 < N) ? W[(size_t)(k0 + wr) * N + nwc + 2] : 0.f;
            wv.w = (nwc + 3 < N) ? W[(size_t)(k0 + wr) * N + nwc + 3] : 0.f;
        }
    }

    for (int kt = k0; kt < k1; kt += 16) {
        __syncthreads();
        float4 xs = xv[0];
        if (XKS > 0) {
            #pragma unroll
            for (int ss = 1; ss < NXV; ++ss) {
                xs.x += xv[ss].x; xs.y += xv[ss].y;
                xs.z += xv[ss].z; xs.w += xv[ss].w;
            }
            float4 xb = *(const float4*)(xbias + kt + xc * 4);
            xs.x = fmaxf(xs.x + xb.x, 0.f);
            xs.y = fmaxf(xs.y + xb.y, 0.f);
            xs.z = fmaxf(xs.z + xb.z, 0.f);
            xs.w = fmaxf(xs.w + xb.w, 0.f);
        }
        Xs[xc * 4 + 0][xr] = xs.x;
        Xs[xc * 4 + 1][xr] = xs.y;
        Xs[xc * 4 + 2][xr] = xs.z;
        Xs[xc * 4 + 3][xr] = xs.w;
        *(float4*)&Ws[wr][wc * 4] = wv;
        __syncthreads();
        if (kt + 16 < k1) {
            const size_t xo = xrow + kt + 16 + xc * 4;
            #pragma unroll
            for (int ss = 0; ss < NXV; ++ss)
                xv[ss] = *(const float4*)(X + (size_t)ss * MK + xo);
            if (nwc + 3 < N) {
                wv = *(const float4*)(W + (size_t)(kt + 16 + wr) * N + nwc);
            } else {
                wv.x = (nwc + 0 < N) ? W[(size_t)(kt + 16 + wr) * N + nwc + 0] : 0.f;
                wv.y = (nwc + 1 < N) ? W[(size_t)(kt + 16 + wr) * N + nwc + 1] : 0.f;
                wv.z = (nwc + 2 < N) ? W[(size_t)(kt + 16 + wr) * N + nwc + 2] : 0.f;
                wv.w = (nwc + 3 < N) ? W[(size_t)(kt + 16 + wr) * N + nwc + 3] : 0.f;
            }
        }
        #pragma unroll
        for (int kk = 0; kk < 16; ++kk) {
            float4 xr4 = *(const float4*)&Xs[kk][tm * 4];
            float4 wr4 = *(const float4*)&Ws[kk][tn * 4];
            acc[0].x += xr4.x * wr4.x; acc[0].y += xr4.x * wr4.y;
            acc[0].z += xr4.x * wr4.z; acc[0].w += xr4.x * wr4.w;
            acc[1].x += xr4.y * wr4.x; acc[1].y += xr4.y * wr4.y;
            acc[1].z += xr4.y * wr4.z; acc[1].w += xr4.y * wr4.w;
            acc[2].x += xr4.z * wr4.x; acc[2].y += xr4.z * wr4.y;
            acc[2].z += xr4.z * wr4.z; acc[2].w += xr4.z * wr4.w;
            acc[3].x += xr4.w * wr4.x; acc[3].y += xr4.w * wr4.y;
            acc[3].z += xr4.w * wr4.z; acc[3].w += xr4.w * wr4.w;
        }
    }
    const int nbase = n0 + tn * 4;
    #pragma unroll
    for (int r = 0; r < 4; ++r) {
        int row = m0 + tm * 4 + r;
        float* pp = Pt + ((size_t)ks * M + row) * N + nbase;
        if (nbase + 3 < N) {
            *(float4*)pp = acc[r];
        } else {
            float vv[4] = { acc[r].x, acc[r].y, acc[r].z, acc[r].w };
            for (int c = 0; c < 4; ++c) if (nbase + c < N) pp[c] = vv[c];
        }
    }
}

template <int XKS>
__global__ __launch_bounds__(256) void fc_tile_kernel(const float* __restrict__ X,
        const float* __restrict__ xbias, const float* __restrict__ W,
        float* __restrict__ Pt, int M, int K, int N, int Kc, int ntiles) {
    __shared__ __align__(16) float Xs[16][68];
    __shared__ __align__(16) float Ws[16][68];
    fc_tile_body<XKS>(X, xbias, W, Pt, M, K, N, Kc, ntiles, blockIdx.x, Xs, Ws);
}

// Sum KS partial slices + bias (+ReLU). R6-verified. N % 4 == 0.
__global__ __launch_bounds__(256) void reduce_bias_kernel(const float* __restrict__ P,
        const float* __restrict__ bias, float* __restrict__ Y,
        int MN, int N, int KS, int do_relu) {
    int i = (blockIdx.x * 256 + threadIdx.x) * 4;
    if (i >= MN) return;
    float4 a = *(const float4*)(P + i);
    for (int s = 1; s < KS; ++s) {
        float4 b = *(const float4*)(P + (size_t)s * MN + i);
        a.x += b.x; a.y += b.y; a.z += b.z; a.w += b.w;
    }
    int n = i - (i / N) * N;
    float4 bb = *(const float4*)(bias + n);
    a.x += bb.x; a.y += bb.y; a.z += bb.z; a.w += bb.w;
    if (do_relu) {
        a.x = fmaxf(a.x, 0.f); a.y = fmaxf(a.y, 0.f);
        a.z = fmaxf(a.z, 0.f); a.w = fmaxf(a.w, 0.f);
    }
    *(float4*)(Y + i) = a;
}

// ---------------------------------------------------------------------------
// proj_body: projection GEMM task (TK=8, verified R6..R14). Bias fused.
// ---------------------------------------------------------------------------
struct ProjParams {
    const float* W[5];
    const float* bp[5];
    const float* g[5];
    const float* be[5];
    int K[5];
    int poff[5];
};

__device__ void proj_body(const ProjParams& P, const float* __restrict__ pools,
        float* __restrict__ proj_out, int task,
        float (*Xs)[68], float (*Ws)[68]) {
    const int st  = task >> 5;
    const int bid = task & 31;
    const int K  = P.K[st];
    const float* X = pools + P.poff[st];
    const float* W = P.W[st];
    const int N = 512;
    int mt  = bid >> 3;
    int nt  = bid & 7;
    const int m0 = mt * 64, n0 = nt * 64;

    const int tid = threadIdx.x;
    const int tm = tid & 15;
    const int tn = tid >> 4;
    const int xa = tid >> 3, xb = tid & 7;
    const int wc = tid & 63, wb = tid >> 6;
    const int nw = n0 + wc;

    float4 acc[4];
    #pragma unroll
    for (int r = 0; r < 4; ++r) acc[r] = make_float4(0.f, 0.f, 0.f, 0.f);

    float x0, x1, w0v, w1v;
    x0  = X[(size_t)(m0 + xa) * K + xb];
    x1  = X[(size_t)(m0 + xa + 32) * K + xb];
    w0v = W[(size_t)wb * N + nw];
    w1v = W[(size_t)(wb + 4) * N + nw];

    for (int kt = 0; kt < K; kt += 8) {
        __syncthreads();
        Xs[xb][xa] = x0; Xs[xb][xa + 32] = x1;
        Ws[wb][wc] = w0v; Ws[wb + 4][wc] = w1v;
        __syncthreads();
        if (kt + 8 < K) {
            x0  = X[(size_t)(m0 + xa) * K + kt + 8 + xb];
            x1  = X[(size_t)(m0 + xa + 32) * K + kt + 8 + xb];
            w0v = W[(size_t)(kt + 8 + wb) * N + nw];
            w1v = W[(size_t)(kt + 8 + wb + 4) * N + nw];
        }
        #pragma unroll
        for (int kk = 0; kk < 8; ++kk) {
            float4 xr = *(const float4*)&Xs[kk][tm * 4];
            float4 wr = *(const float4*)&Ws[kk][tn * 4];
            acc[0].x += xr.x * wr.x; acc[0].y += xr.x * wr.y;
            acc[0].z += xr.x * wr.z; acc[0].w += xr.x * wr.w;
            acc[1].x += xr.y * wr.x; acc[1].y += xr.y * wr.y;
            acc[1].z += xr.y * wr.z; acc[1].w += xr.y * wr.w;
            acc[2].x += xr.z * wr.x; acc[2].y += xr.z * wr.y;
            acc[2].z += xr.z * wr.z; acc[2].w += xr.z * wr.w;
            acc[3].x += xr.w * wr.x; acc[3].y += xr.w * wr.y;
            acc[3].z += xr.w * wr.z; acc[3].w += xr.w * wr.w;
        }
    }
    const int nbase = n0 + tn * 4;
    float4 bb = *(const float4*)(P.bp[st] + nbase);
    float* op = proj_out + (size_t)st * 131072 + (size_t)(m0 + tm * 4) * N + nbase;
    #pragma unroll
    for (int r = 0; r < 4; ++r) {
        float4 v = acc[r];
        v.x += bb.x; v.y += bb.y; v.z += bb.z; v.w += bb.w;
        *(float4*)(op + (size_t)r * N) = v;
    }
}

// gate1 split-K (512 blocks) + proj (160 tasks) merged: independent work.
__global__ __launch_bounds__(256) void gate1_proj_kernel(
        const float* __restrict__ gate_in, const float* __restrict__ Wg1,
        float* __restrict__ slab, ProjParams P,
        const float* __restrict__ pools, float* __restrict__ proj_out) {
    __shared__ __align__(16) float Xs[16][68];
    __shared__ __align__(16) float Ws[16][68];
    if (blockIdx.x < 512) {
        fc_tile_body<0>(gate_in, nullptr, Wg1, slab, 256, 960, 1024, 128, 16,
                        blockIdx.x, Xs, Ws);
    } else {
        proj_body(P, pools, proj_out, blockIdx.x - 512,
                  (float(*)[68])Xs, (float(*)[68])Ws);
    }
}

// ---------------------------------------------------------------------------
// fc3 + mixln fused; fc3 input = gate2's 16 partial slices, reduced inline
// (ascending s + bg2 + relu — identical order to reduce_bias).
// ---------------------------------------------------------------------------
__global__ __launch_bounds__(256) void fc3_mixln_kernel(
        const float* __restrict__ Xp, const float* __restrict__ bg2,
        const float* __restrict__ Wg3, const float* __restrict__ bg3,
        ProjParams P, const float* __restrict__ proj_out,
        float* __restrict__ mix, float* __restrict__ out_gl,
        float* __restrict__ out_topi, float* __restrict__ out_w) {
    const int b    = blockIdx.x;
    const int tid  = threadIdx.x;
    const int lane = tid & 63;
    const int wv   = tid >> 6;
    __shared__ float red[4][5];
    __shared__ int   s_i0, s_i1;
    __shared__ float s_w0, s_w1;
    __shared__ float redS[4], redQ[4];
    __shared__ float s_mu, s_rstd;

    // ---- phase 1: gate fc3 (inline 16-slice reduce) + top2 + softmax ----
    {
        const size_t MK = (size_t)256 * 512;
        float acc[5] = {0.f, 0.f, 0.f, 0.f, 0.f};
        for (int k = tid; k < 512; k += 256) {
            float v = Xp[(size_t)b * 512 + k];
            #pragma unroll
            for (int s = 1; s < 16; ++s)
                v += Xp[(size_t)s * MK + (size_t)b * 512 + k];
            float xv = fmaxf(v + bg2[k], 0.f);
            const float* wr = Wg3 + (size_t)k * 5;
            acc[0] += xv * wr[0]; acc[1] += xv * wr[1]; acc[2] += xv * wr[2];
            acc[3] += xv * wr[3]; acc[4] += xv * wr[4];
        }
        #pragma unroll
        for (int off = 32; off > 0; off >>= 1) {
            #pragma unroll
            for (int j = 0; j < 5; ++j) acc[j] += __shfl_down(acc[j], off, 64);
        }
        if (lane == 0) {
            #pragma unroll
            for (int j = 0; j < 5; ++j) red[wv][j] = acc[j];
        }
        __syncthreads();
        if (tid == 0) {
            float v[5];
            #pragma unroll
            for (int j = 0; j < 5; ++j)
                v[j] = ((red[0][j] + red[1][j]) + (red[2][j] + red[3][j])) + bg3[j];
            int i0 = 0;
            #pragma unroll
            for (int i = 1; i < 5; ++i) if (v[i] > v[i0]) i0 = i;
            int i1 = -1;
            #pragma unroll
            for (int i = 0; i < 5; ++i) {
                if (i == i0) continue;
                if (i1 < 0 || v[i] > v[i1]) i1 = i;
            }
            float e1 = __expf(v[i1] - v[i0]);
            float inv = 1.f / (1.f + e1);
            float w0 = inv, w1 = e1 * inv;
            s_i0 = i0; s_i1 = i1; s_w0 = w0; s_w1 = w1;
            #pragma unroll
            for (int j = 0; j < 5; ++j) out_gl[b * 5 + j] = v[j];
            out_topi[b * 2]     = (float)i0;
            out_topi[b * 2 + 1] = (float)i1;
            out_w[b * 2]     = w0;
            out_w[b * 2 + 1] = w1;
        }
    }
    __syncthreads();

    // ---- phase 2: mixln (f = tid and tid+256) ----
    float a0 = 0.f, a1 = 0.f;
    const int i0 = s_i0, i1 = s_i1;
    const float w0 = s_w0, w1 = s_w1;
    for (int j = 0; j < 2; ++j) {
        __syncthreads();
        const int st = j ? i1 : i0;
        const float w = j ? w1 : w0;
        const float* pp = proj_out + (size_t)st * 131072 + (size_t)b * 512;
        float h0 = pp[tid];
        float h1 = pp[tid + 256];
        float s = h0 + h1, q = h0 * h0 + h1 * h1;
        #pragma unroll
        for (int off = 32; off > 0; off >>= 1) {
            s += __shfl_down(s, off, 64);
            q += __shfl_down(q, off, 64);
        }
        if (lane == 0) { redS[wv] = s; redQ[wv] = q; }
        __syncthreads();
        if (tid == 0) {
            float ts = (redS[0] + redS[1]) + (redS[2] + redS[3]);
            float tq = (redQ[0] + redQ[1]) + (redQ[2] + redQ[3]);
            float mu  = ts * (1.f / 512.f);
            float var = tq * (1.f / 512.f) - mu * mu;
            s_mu   = mu;
            s_rstd = rsqrtf(var + 1e-5f);
        }
        __syncthreads();
        float mu = s_mu, rstd = s_rstd;
        float x0 = (h0 - mu) * rstd * P.g[st][tid] + P.be[st][tid];
        float x1 = (h1 - mu) * rstd * P.g[st][tid + 256] + P.be[st][tid + 256];
        a0 += w * (0.5f * x0 * (1.f + erff(x0 * 0.70710678118654752f)));
        a1 += w * (0.5f * x1 * (1.f + erff(x1 * 0.70710678118654752f)));
    }
    mix[(size_t)b * 512 + tid]       = a0;
    mix[(size_t)b * 512 + tid + 256] = a1;
}

// ---------------------------------------------------------------------------
extern "C" void kernel_launch(void* const* d_in, const int* in_sizes, int n_in,
                              void* d_out, int out_size, void* d_ws, size_t ws_size,
                              hipStream_t stream) {
    const int B = 256;

    const float* s1 = (const float*)d_in[0];
    const float* s2 = (const float*)d_in[1];
    const float* s3 = (const float*)d_in[2];
    const float* s4 = (const float*)d_in[3];
    const float* s5 = (const float*)d_in[4];
    const float* ff = (const float*)d_in[5];
    const float *Wp[5], *bp[5], *g[5], *be[5];
    for (int i = 0; i < 5; ++i) {
        Wp[i] = (const float*)d_in[6 + 4 * i];
        bp[i] = (const float*)d_in[7 + 4 * i];
        g[i]  = (const float*)d_in[8 + 4 * i];
        be[i] = (const float*)d_in[9 + 4 * i];
    }
    const float* Wg1 = (const float*)d_in[26]; const float* bg1 = (const float*)d_in[27];
    const float* Wg2 = (const float*)d_in[28]; const float* bg2 = (const float*)d_in[29];
    const float* Wg3 = (const float*)d_in[30]; const float* bg3 = (const float*)d_in[31];
    const float* Wc1 = (const float*)d_in[32]; const float* bc1 = (const float*)d_in[33];
    const float* Wc2 = (const float*)d_in[34]; const float* bc2 = (const float*)d_in[35];
    const float* Wc3 = (const float*)d_in[36]; const float* bc3 = (const float*)d_in[37];

    // ---- workspace layout (fp32 elements) ----
    float* ws = (float*)d_ws;
    const int Ks[5]   = {16, 24, 40, 80, 160};
    const int poff[5] = {0, 4096, 10240, 20480, 40960};
    float* pools    = ws;                                     // 81920
    float* gate_in  = ws + 81920;                             // 245760
    float* mix      = ws + 327680;                            // 131072
    float* proj_out = ws + 458752;                            // 655360
    float* slabA    = ws + 1114112;                           // 2097152
    float* slabB    = ws + 3211264;                           // 2097152

    float* out      = (float*)d_out;
    float* out_gl   = out + 256000;
    float* out_topi = out + 257280;
    float* out_w    = out + 257792;

    // ---- 1) ALL pooling in one dispatch (NT loads) ----
    {
        PoolAll S;
        const float* srcs[4] = { s1, s2, s3, s4 };
        const int rls[4]  = { 112 * 112, 56 * 56, 28 * 28, 14 * 14 };
        const int rows[4] = { B * 16, B * 24, B * 40, B * 80 };
        int cum = 0;
        for (int i = 0; i < 4; ++i) {
            S.src[i] = srcs[i]; S.dst[i] = pools + poff[i]; S.n4[i] = rls[i] / 4;
            cum += rows[i]; S.cum[i] = cum; S.inv[i] = 1.f / rls[i];
        }
        S.nbb   = (cum * 64) / 256;           // 10240
        S.s5    = s5; S.ff = ff;
        S.dst5  = pools + poff[4]; S.dstf = gate_in;
        S.rows5 = B * 160;
        int small_blocks = (S.rows5 + B * 960) / 64;   // 4480
        pool_all_kernel<<<S.nbb + small_blocks, 256, 0, stream>>>(S);
    }

    ProjParams P;
    for (int i = 0; i < 5; ++i) {
        P.W[i] = Wp[i]; P.bp[i] = bp[i]; P.g[i] = g[i]; P.be[i] = be[i];
        P.K[i] = Ks[i]; P.poff[i] = poff[i];
    }

    // ---- 2) gate1 split-K (KS=8, 512 blocks) + proj, one dispatch -> slabA
    gate1_proj_kernel<<<512 + 160, 256, 0, stream>>>(gate_in, Wg1, slabA,
                                                     P, pools, proj_out);
    // ---- 3) gate2: XKS=8 fused reduce(bg1,relu), KS=16 (512 blocks) -> slabB
    fc_tile_kernel<8><<<16 * 4 * 8, 256, 0, stream>>>(
        slabA, bg1, Wg2, slabB, 256, 1024, 512, 64, 8);
    // ---- 4) fc3 (inline 16-slice reduce + bg2 + relu) + top2 + mixln ----
    fc3_mixln_kernel<<<B, 256, 0, stream>>>(slabB, bg2, Wg3, bg3, P, proj_out,
                                            mix, out_gl, out_topi, out_w);
    // ---- 5) cls1: KS=8 (512 blocks) -> slabA
    fc_tile_kernel<0><<<8 * 4 * 16, 256, 0, stream>>>(
        mix, nullptr, Wc1, slabA, 256, 512, 1024, 64, 16);
    // ---- 6) cls2: XKS=8 fused reduce(bc1,relu), KS=8 Kc=128 (256 blocks) -> slabB
    fc_tile_kernel<8><<<8 * 4 * 8, 256, 0, stream>>>(
        slabA, bc1, Wc2, slabB, 256, 1024, 512, 128, 8);
    // ---- 7) cls3: XKS=8 fused reduce(bc2,relu), KS=8 (512 blocks) -> slabA
    fc_tile_kernel<8><<<8 * 4 * 16, 256, 0, stream>>>(
        slabB, bc2, Wc3, slabA, 256, 512, 1000, 64, 16);
    // ---- 8) final reduce + bc3 -> out logits
    reduce_bias_kernel<<<(256 * 1000 / 4 + 255) / 256, 256, 0, stream>>>(
        slabA, bc3, out, 256 * 1000, 1000, 8, 0);
}